// Round 1
// baseline (389.027 us; speedup 1.0000x reference)
//
#include <hip/hip_runtime.h>
#include <hip/hip_bf16.h>
#include <stdint.h>

#define CIN 2048
#define HID 512
#define NPOS 2048
#define NNEG 2048

typedef __attribute__((ext_vector_type(8))) short s16x8;
typedef __attribute__((ext_vector_type(4))) float f32x4;
typedef unsigned short ushort_t;

static __device__ __forceinline__ float bf2f(unsigned short u) {
    union { float f; unsigned int i; } v; v.i = ((unsigned int)u) << 16; return v.f;
}
static __device__ __forceinline__ unsigned short f2bf(float f) {
    union { float f; unsigned int i; } v; v.f = f;
    unsigned int r = v.i + 0x7FFF + ((v.i >> 16) & 1);  // RNE
    return (unsigned short)(r >> 16);
}

typedef __attribute__((address_space(1))) const void gvoid_t;
typedef __attribute__((address_space(3))) void lvoid_t;
static __device__ __forceinline__ void gload16(const void* g, void* l) {
    __builtin_amdgcn_global_load_lds((gvoid_t*)g, (lvoid_t*)l, 16, 0, 0);
}

// ---------------- pass 1: NCHW f32 -> padded NHWC bf16 ----------------
// Fp[b][Y][X][ic], Y,X in [0,18), interior at Y=y+1,X=x+1. Border pre-zeroed by memset.
__global__ __launch_bounds__(256) void k_prep_fmap(const float* __restrict__ F,
                                                   ushort_t* __restrict__ Fp) {
    int b = blockIdx.x >> 4;
    int y = blockIdx.x & 15;
    int t = threadIdx.x;
    __shared__ float tile[64][17];
    for (int ic0 = 0; ic0 < CIN; ic0 += 64) {
#pragma unroll
        for (int i = 0; i < 4; ++i) {
            int r = i * 256 + t;
            int ci = r >> 4, x = r & 15;
            tile[ci][x] = F[((b * CIN + ic0 + ci) * 16 + y) * 16 + x];
        }
        __syncthreads();
#pragma unroll
        for (int i = 0; i < 4; ++i) {
            int o = i * 256 + t;
            int x = o >> 6, ci = o & 63;
            Fp[((size_t)(b * 18 + y + 1) * 18 + (x + 1)) * CIN + ic0 + ci] = f2bf(tile[ci][x]);
        }
        __syncthreads();
    }
}

// ---------------- pass 2: W1[oc][ic][3][3] f32 -> Wt2[k][oc][ic] bf16 ----------------
__global__ __launch_bounds__(256) void k_prep_w(const float* __restrict__ W1,
                                                ushort_t* __restrict__ Wt2) {
    int oc = blockIdx.x;
    int t = threadIdx.x;
    __shared__ float buf[512 * 9];
    for (int ic0 = 0; ic0 < CIN; ic0 += 512) {
        const float* src = W1 + ((size_t)oc * CIN + ic0) * 9;
        for (int i = t; i < 512 * 9; i += 256) buf[i] = src[i];
        __syncthreads();
#pragma unroll
        for (int k = 0; k < 9; ++k) {
            ushort_t* dst = Wt2 + ((size_t)(k * HID + oc)) * CIN + ic0;
            for (int i = t; i < 512; i += 256) dst[i] = f2bf(buf[i * 9 + k]);
        }
        __syncthreads();
    }
}

// ---------------- pass 3: implicit-GEMM conv + bias + ReLU -> Out[4096][512] bf16 ----
#define BM 128
#define BN 64
#define BK 64

__global__ __launch_bounds__(256) void k_gemm(const ushort_t* __restrict__ Fp,
                                              const ushort_t* __restrict__ Wt2,
                                              const float* __restrict__ b1,
                                              ushort_t* __restrict__ Out) {
    __shared__ __align__(16) ushort_t As[BM * BK];  // 16 KB
    __shared__ __align__(16) ushort_t Bs[BN * BK];  //  8 KB

    int bid = blockIdx.x;
    int cb = bid & 7, rb = bid >> 3;
    int m0 = rb * BM, oc0 = cb * BN;
    int t = threadIdx.x;
    int w = t >> 6, lane = t & 63;
    int wr = w >> 1, wc = w & 1;

    f32x4 acc[4][2];
#pragma unroll
    for (int a = 0; a < 4; ++a)
#pragma unroll
        for (int b = 0; b < 2; ++b) acc[a][b] = (f32x4){0.f, 0.f, 0.f, 0.f};

    // per-thread A staging decomposition (4 lane-loads / thread / K-step)
    int Ab[4], Ay[4], Ax[4], Aseg[4];
#pragma unroll
    for (int i = 0; i < 4; ++i) {
        int li = i * 256 + t;
        int gr = li >> 3;
        Aseg[i] = li & 7;
        int m = m0 + gr;
        Ab[i] = m >> 8;
        Ay[i] = (m >> 4) & 15;
        Ax[i] = m & 15;
    }

    for (int kidx = 0; kidx < 9; ++kidx) {
        int ky = kidx / 3;
        int kx = kidx - 3 * ky;
        int Arow[4];
#pragma unroll
        for (int i = 0; i < 4; ++i)
            Arow[i] = ((Ab[i] * 18 + Ay[i] + ky) * 18 + (Ax[i] + kx)) * CIN + Aseg[i] * 8;
        int Brow[2];
#pragma unroll
        for (int i = 0; i < 2; ++i) {
            int li = i * 256 + t;
            int gr = li >> 3, seg = li & 7;
            Brow[i] = (kidx * HID + oc0 + gr) * CIN + seg * 8;
        }

        for (int ic0 = 0; ic0 < CIN; ic0 += BK) {
#pragma unroll
            for (int i = 0; i < 4; ++i)
                gload16(Fp + Arow[i] + ic0, &As[(size_t)(i * 256 + t) * 8]);
#pragma unroll
            for (int i = 0; i < 2; ++i)
                gload16(Wt2 + Brow[i] + ic0, &Bs[(size_t)(i * 256 + t) * 8]);
            __syncthreads();

            s16x8 af[4][2], bf[2][2];
#pragma unroll
            for (int ks = 0; ks < 2; ++ks) {
#pragma unroll
                for (int fm = 0; fm < 4; ++fm)
                    af[fm][ks] = *(const s16x8*)&As[(wr * 64 + fm * 16 + (lane & 15)) * BK +
                                                   ks * 32 + (lane >> 4) * 8];
#pragma unroll
                for (int fn = 0; fn < 2; ++fn)
                    bf[fn][ks] = *(const s16x8*)&Bs[(wc * 32 + fn * 16 + (lane & 15)) * BK +
                                                   ks * 32 + (lane >> 4) * 8];
            }
#pragma unroll
            for (int fm = 0; fm < 4; ++fm)
#pragma unroll
                for (int fn = 0; fn < 2; ++fn)
#pragma unroll
                    for (int ks = 0; ks < 2; ++ks)
                        acc[fm][fn] = __builtin_amdgcn_mfma_f32_16x16x32_bf16(
                            af[fm][ks], bf[fn][ks], acc[fm][fn], 0, 0, 0);
            __syncthreads();
        }
    }

    // epilogue: + b1, ReLU, store bf16
#pragma unroll
    for (int fm = 0; fm < 4; ++fm)
#pragma unroll
        for (int fn = 0; fn < 2; ++fn)
#pragma unroll
            for (int r = 0; r < 4; ++r) {
                int gm = m0 + wr * 64 + fm * 16 + (lane >> 4) * 4 + r;
                int gn = oc0 + wc * 32 + fn * 16 + (lane & 15);
                float v = acc[fm][fn][r] + b1[gn];
                v = fmaxf(v, 0.f);
                Out[(size_t)gm * HID + gn] = f2bf(v);
            }
}

// ---------------- pass 4: 1x1 heads -> conf[4096][9], reg[4096][36] f32 --------------
__global__ __launch_bounds__(256) void k_heads(const ushort_t* __restrict__ Out,
                                               const float* __restrict__ Wc,
                                               const float* __restrict__ bc,
                                               const float* __restrict__ Wr,
                                               const float* __restrict__ br,
                                               float* __restrict__ conf,
                                               float* __restrict__ reg) {
    int w = threadIdx.x >> 6, lane = threadIdx.x & 63;
    int m = blockIdx.x * 4 + w;
    s16x8 rv = *(const s16x8*)&Out[(size_t)m * HID + lane * 8];
    float ov[8];
#pragma unroll
    for (int j = 0; j < 8; ++j) ov[j] = bf2f((unsigned short)rv[j]);
#pragma unroll 1
    for (int o = 0; o < 45; ++o) {
        const float* Wrow = (o < 9) ? (Wc + o * HID) : (Wr + (size_t)(o - 9) * HID);
        float p = 0.f;
#pragma unroll
        for (int j = 0; j < 8; ++j) p += ov[j] * Wrow[lane * 8 + j];
#pragma unroll
        for (int s = 32; s > 0; s >>= 1) p += __shfl_xor(p, s);
        if (lane == 0) {
            if (o < 9)
                conf[m * 9 + o] = p + bc[o];
            else
                reg[m * 36 + (o - 9)] = p + br[o - 9];
        }
    }
}

// ---------------- pass 5: gathers + proposals + losses ------------------------------
static __device__ __forceinline__ float softplus(float x) {
    return log1pf(expf(-fabsf(x))) + fmaxf(x, 0.f);
}

__global__ __launch_bounds__(256) void k_loss(const float* __restrict__ conf,
                                              const float* __restrict__ reg,
                                              const int* __restrict__ pos_ind,
                                              const int* __restrict__ neg_ind,
                                              const float* __restrict__ anc,
                                              const float* __restrict__ gt,
                                              float* __restrict__ out) {
    int t = threadIdx.x;
    float cls = 0.f, rloss = 0.f;
    for (int p = t; p < NPOS; p += 256) {
        int ind = pos_ind[p];
        {  // conf gather: flat index over [B,9,16,16]
            int b = ind / 2304, r = ind % 2304;
            int c = r >> 8, r2 = r & 255;
            float cv = conf[(b * 256 + r2) * 9 + c];
            cls += softplus(-cv);
        }
        float off[4];
#pragma unroll
        for (int j = 0; j < 4; ++j) {  // reg.reshape(-1,4)[ind]: 4 consecutive flat elems of [B,36,16,16]
            int e = 4 * ind + j;
            int b = e / 9216, r = e % 9216;
            int c = r >> 8, r2 = r & 255;
            off[j] = reg[(b * 256 + r2) * 36 + c];
        }
        float ax1 = anc[4 * p], ay1 = anc[4 * p + 1], ax2 = anc[4 * p + 2], ay2 = anc[4 * p + 3];
        float acx = (ax1 + ax2) * 0.5f, acy = (ay1 + ay2) * 0.5f;
        float aw = ax2 - ax1, ah = ay2 - ay1;
        float pcx = acx + off[0] * aw, pcy = acy + off[1] * ah;
        float pw = aw * expf(off[2]), ph = ah * expf(off[3]);
        out[1 + 4 * p + 0] = pcx - pw * 0.5f;
        out[1 + 4 * p + 1] = pcy - ph * 0.5f;
        out[1 + 4 * p + 2] = pcx + pw * 0.5f;
        out[1 + 4 * p + 3] = pcy + ph * 0.5f;
        float gx1 = gt[4 * p], gy1 = gt[4 * p + 1], gx2 = gt[4 * p + 2], gy2 = gt[4 * p + 3];
        float gcx = (gx1 + gx2) * 0.5f, gcy = (gy1 + gy2) * 0.5f;
        float gw = gx2 - gx1, gh = gy2 - gy1;
        float tv[4];
        tv[0] = (gcx - acx) / aw;
        tv[1] = (gcy - acy) / ah;
        tv[2] = logf(gw / aw);
        tv[3] = logf(gh / ah);
#pragma unroll
        for (int j = 0; j < 4; ++j) {
            float d = off[j] - tv[j];
            float ad = fabsf(d);
            rloss += (ad < 1.f) ? 0.5f * d * d : ad - 0.5f;
        }
    }
    for (int q = t; q < NNEG; q += 256) {
        int ind = neg_ind[q];
        int b = ind / 2304, r = ind % 2304;
        int c = r >> 8, r2 = r & 255;
        float cv = conf[(b * 256 + r2) * 9 + c];
        cls += softplus(cv);
    }
    __shared__ float s1[256], s2[256];
    s1[t] = cls;
    s2[t] = rloss;
    __syncthreads();
    for (int s = 128; s > 0; s >>= 1) {
        if (t < s) {
            s1[t] += s1[t + s];
            s2[t] += s2[t + s];
        }
        __syncthreads();
    }
    if (t == 0) out[0] = (s1[0] + 5.f * s2[0]) / 16.f;
}

extern "C" void kernel_launch(void* const* d_in, const int* in_sizes, int n_in,
                              void* d_out, int out_size, void* d_ws, size_t ws_size,
                              hipStream_t stream) {
    const float* F   = (const float*)d_in[0];
    const float* anc = (const float*)d_in[1];
    const float* gt  = (const float*)d_in[2];
    const float* W1  = (const float*)d_in[3];
    const float* b1  = (const float*)d_in[4];
    const float* Wc  = (const float*)d_in[5];
    const float* bc  = (const float*)d_in[6];
    const float* Wr  = (const float*)d_in[7];
    const float* br  = (const float*)d_in[8];
    const int* pos_ind = (const int*)d_in[9];
    const int* neg_ind = (const int*)d_in[10];
    float* out = (float*)d_out;

    char* ws = (char*)d_ws;
    const size_t FP_BYTES  = (size_t)16 * 18 * 18 * CIN * 2;  // 21,233,664
    const size_t WT_BYTES  = (size_t)9 * HID * CIN * 2;       // 18,874,368
    const size_t OUT_BYTES = (size_t)4096 * HID * 2;          //  4,194,304
    ushort_t* Fp   = (ushort_t*)ws;
    ushort_t* Wt2  = (ushort_t*)(ws + FP_BYTES);
    ushort_t* OutB = (ushort_t*)(ws + FP_BYTES + WT_BYTES);
    float* conf = (float*)(ws + FP_BYTES + WT_BYTES + OUT_BYTES);
    float* reg  = (float*)(ws + FP_BYTES + WT_BYTES + OUT_BYTES + (size_t)4096 * 9 * 4);

    hipMemsetAsync(Fp, 0, FP_BYTES, stream);
    k_prep_fmap<<<256, 256, 0, stream>>>(F, Fp);
    k_prep_w<<<512, 256, 0, stream>>>(W1, Wt2);
    k_gemm<<<256, 256, 0, stream>>>(Fp, Wt2, b1, OutB);
    k_heads<<<1024, 256, 0, stream>>>(OutB, Wc, bc, Wr, br, conf, reg);
    k_loss<<<1, 256, 0, stream>>>(conf, reg, pos_ind, neg_ind, anc, gt, out);
}

// Round 2
// 189.434 us; speedup vs baseline: 2.0536x; 2.0536x over previous
//
#include <hip/hip_runtime.h>
#include <hip/hip_bf16.h>
#include <stdint.h>

#define CIN 2048
#define HID 512
#define NPOS 2048
#define NNEG 2048

typedef __attribute__((ext_vector_type(8))) short s16x8;
typedef __attribute__((ext_vector_type(4))) float f32x4;
typedef unsigned short ushort_t;

static __device__ __forceinline__ float bf2f(unsigned short u) {
    union { float f; unsigned int i; } v; v.i = ((unsigned int)u) << 16; return v.f;
}
static __device__ __forceinline__ unsigned short f2bf(float f) {
    union { float f; unsigned int i; } v; v.f = f;
    unsigned int r = v.i + 0x7FFF + ((v.i >> 16) & 1);  // RNE
    return (unsigned short)(r >> 16);
}

typedef __attribute__((address_space(1))) const void gvoid_t;
typedef __attribute__((address_space(3))) void lvoid_t;
static __device__ __forceinline__ void gload16(const void* g, void* l) {
    __builtin_amdgcn_global_load_lds((gvoid_t*)g, (lvoid_t*)l, 16, 0, 0);
}

// ---------------- pass 1: NCHW f32 -> padded NHWC bf16 ----------------
// Fp[b][Y][X][ic], Y,X in [0,18), interior at Y=y+1,X=x+1. Border pre-zeroed by memset.
__global__ __launch_bounds__(256) void k_prep_fmap(const float* __restrict__ F,
                                                   ushort_t* __restrict__ Fp) {
    int b = blockIdx.x >> 4;
    int y = blockIdx.x & 15;
    int t = threadIdx.x;
    __shared__ float tile[64][17];
    for (int ic0 = 0; ic0 < CIN; ic0 += 64) {
#pragma unroll
        for (int i = 0; i < 4; ++i) {
            int r = i * 256 + t;
            int ci = r >> 4, x = r & 15;
            tile[ci][x] = F[((b * CIN + ic0 + ci) * 16 + y) * 16 + x];
        }
        __syncthreads();
#pragma unroll
        for (int i = 0; i < 4; ++i) {
            int o = i * 256 + t;
            int x = o >> 6, ci = o & 63;
            Fp[((size_t)(b * 18 + y + 1) * 18 + (x + 1)) * CIN + ic0 + ci] = f2bf(tile[ci][x]);
        }
        __syncthreads();
    }
}

// ---------------- pass 2: W1[oc][ic][3][3] f32 -> Wt2[k][oc][ic] bf16 ----------------
__global__ __launch_bounds__(256) void k_prep_w(const float* __restrict__ W1,
                                                ushort_t* __restrict__ Wt2) {
    int oc = blockIdx.x;
    int t = threadIdx.x;
    __shared__ float buf[512 * 9];
    for (int ic0 = 0; ic0 < CIN; ic0 += 512) {
        const float* src = W1 + ((size_t)oc * CIN + ic0) * 9;
        for (int i = t; i < 512 * 9; i += 256) buf[i] = src[i];
        __syncthreads();
#pragma unroll
        for (int k = 0; k < 9; ++k) {
            ushort_t* dst = Wt2 + ((size_t)(k * HID + oc)) * CIN + ic0;
            for (int i = t; i < 512; i += 256) dst[i] = f2bf(buf[i * 9 + k]);
        }
        __syncthreads();
    }
}

// ---------------- pass 3: split-K implicit-GEMM conv -> Part[ns][4096][512] f32 ------
#define BM 128
#define BN 64
#define BK 64

__global__ __launch_bounds__(256) void k_gemm(const ushort_t* __restrict__ Fp,
                                              const ushort_t* __restrict__ Wt2,
                                              float* __restrict__ Part, int icLen) {
    __shared__ __align__(16) ushort_t As[BM * BK];  // 16 KB
    __shared__ __align__(16) ushort_t Bs[BN * BK];  //  8 KB

    int bid = blockIdx.x;
    int cb = bid & 7;           // column block -> XCD pin (bid%8)
    int tmp = bid >> 3;
    int rb = tmp & 31;
    int split = tmp >> 5;
    int icBase = split * icLen;
    int m0 = rb * BM, oc0 = cb * BN;
    int t = threadIdx.x;
    int w = t >> 6, lane = t & 63;
    int wr = w >> 1, wc = w & 1;
    int hi = lane >> 4;

    f32x4 acc[4][2];
#pragma unroll
    for (int a = 0; a < 4; ++a)
#pragma unroll
        for (int b = 0; b < 2; ++b) acc[a][b] = (f32x4){0.f, 0.f, 0.f, 0.f};

    // A staging bases: 4 lane-loads/thread; pre-swizzled global segment (T2, rule #21)
    int Abase[4];
#pragma unroll
    for (int i = 0; i < 4; ++i) {
        int li = i * 256 + t;
        int gr = li >> 3;                 // LDS row 0..127
        int sg = (li & 7) ^ (gr & 7);     // swizzled global 16B segment
        int m = m0 + gr;
        int b = m >> 8, y = (m >> 4) & 15, x = m & 15;
        Abase[i] = ((b * 18 + y) * 18 + x) * CIN + sg * 8;
    }
    // B staging bases: 2 lane-loads/thread
    int Bbase[2];
#pragma unroll
    for (int i = 0; i < 2; ++i) {
        int li = i * 256 + t;
        int gr = li >> 3;                 // LDS row 0..63
        int sg = (li & 7) ^ (gr & 7);
        Bbase[i] = (oc0 + gr) * CIN + sg * 8;
    }
    // swizzled ds_read element indices
    int aidx[4][2], bidx[2][2];
#pragma unroll
    for (int fm = 0; fm < 4; ++fm)
#pragma unroll
        for (int ks = 0; ks < 2; ++ks) {
            int r = wr * 64 + fm * 16 + (lane & 15);
            aidx[fm][ks] = r * BK + ((ks * 32 + hi * 8) ^ ((r & 7) << 3));
        }
#pragma unroll
    for (int fn = 0; fn < 2; ++fn)
#pragma unroll
        for (int ks = 0; ks < 2; ++ks) {
            int r = wc * 32 + fn * 16 + (lane & 15);
            bidx[fn][ks] = r * BK + ((ks * 32 + hi * 8) ^ ((r & 7) << 3));
        }

    for (int ic0 = icBase; ic0 < icBase + icLen; ic0 += BK) {
#pragma unroll 1
        for (int kidx = 0; kidx < 9; ++kidx) {
            int ky = kidx / 3, kx = kidx - 3 * ky;
            int koff = (ky * 18 + kx) * CIN + ic0;
            int bko = kidx * HID * CIN + ic0;
#pragma unroll
            for (int i = 0; i < 4; ++i)
                gload16(Fp + Abase[i] + koff, &As[(size_t)(i * 256 + t) * 8]);
#pragma unroll
            for (int i = 0; i < 2; ++i)
                gload16(Wt2 + Bbase[i] + bko, &Bs[(size_t)(i * 256 + t) * 8]);
            __syncthreads();

            s16x8 af[4][2], bf[2][2];
#pragma unroll
            for (int ks = 0; ks < 2; ++ks) {
#pragma unroll
                for (int fm = 0; fm < 4; ++fm) af[fm][ks] = *(const s16x8*)&As[aidx[fm][ks]];
#pragma unroll
                for (int fn = 0; fn < 2; ++fn) bf[fn][ks] = *(const s16x8*)&Bs[bidx[fn][ks]];
            }
#pragma unroll
            for (int fm = 0; fm < 4; ++fm)
#pragma unroll
                for (int fn = 0; fn < 2; ++fn)
#pragma unroll
                    for (int ks = 0; ks < 2; ++ks)
                        acc[fm][fn] = __builtin_amdgcn_mfma_f32_16x16x32_bf16(
                            af[fm][ks], bf[fn][ks], acc[fm][fn], 0, 0, 0);
            __syncthreads();
        }
    }

    // epilogue: store f32 partial (bias/ReLU applied in k_finish)
#pragma unroll
    for (int fm = 0; fm < 4; ++fm)
#pragma unroll
        for (int fn = 0; fn < 2; ++fn)
#pragma unroll
            for (int r = 0; r < 4; ++r) {
                int gm = m0 + wr * 64 + fm * 16 + (lane >> 4) * 4 + r;
                int gn = oc0 + wc * 32 + fn * 16 + (lane & 15);
                Part[((size_t)split * 4096 + gm) * HID + gn] = acc[fm][fn][r];
            }
}

// ---------------- pass 4: reduce splits + bias + ReLU + 1x1 heads -------------------
__global__ __launch_bounds__(256) void k_finish(const float* __restrict__ Part, int ns,
                                                const float* __restrict__ b1,
                                                const float* __restrict__ Wc,
                                                const float* __restrict__ bc,
                                                const float* __restrict__ Wr,
                                                const float* __restrict__ br,
                                                float* __restrict__ conf,
                                                float* __restrict__ reg) {
    int w = threadIdx.x >> 6, lane = threadIdx.x & 63;
    int m = blockIdx.x * 4 + w;
    float ov[8];
#pragma unroll
    for (int j = 0; j < 8; ++j) ov[j] = 0.f;
    for (int s = 0; s < ns; ++s) {
        const float4* p = (const float4*)&Part[((size_t)s * 4096 + m) * HID + lane * 8];
        float4 v0 = p[0], v1 = p[1];
        ov[0] += v0.x; ov[1] += v0.y; ov[2] += v0.z; ov[3] += v0.w;
        ov[4] += v1.x; ov[5] += v1.y; ov[6] += v1.z; ov[7] += v1.w;
    }
#pragma unroll
    for (int j = 0; j < 8; ++j) ov[j] = fmaxf(ov[j] + b1[lane * 8 + j], 0.f);
#pragma unroll 1
    for (int o = 0; o < 45; ++o) {
        const float* Wrow = (o < 9) ? (Wc + o * HID) : (Wr + (size_t)(o - 9) * HID);
        float p = 0.f;
#pragma unroll
        for (int j = 0; j < 8; ++j) p += ov[j] * Wrow[lane * 8 + j];
#pragma unroll
        for (int s = 32; s > 0; s >>= 1) p += __shfl_xor(p, s);
        if (lane == 0) {
            if (o < 9)
                conf[m * 9 + o] = p + bc[o];
            else
                reg[m * 36 + (o - 9)] = p + br[o - 9];
        }
    }
}

// ---------------- pass 5: gathers + proposals + losses ------------------------------
static __device__ __forceinline__ float softplus(float x) {
    return log1pf(expf(-fabsf(x))) + fmaxf(x, 0.f);
}

__global__ __launch_bounds__(256) void k_loss(const float* __restrict__ conf,
                                              const float* __restrict__ reg,
                                              const int* __restrict__ pos_ind,
                                              const int* __restrict__ neg_ind,
                                              const float* __restrict__ anc,
                                              const float* __restrict__ gt,
                                              float* __restrict__ out) {
    int t = threadIdx.x;
    float cls = 0.f, rloss = 0.f;
    for (int p = t; p < NPOS; p += 256) {
        int ind = pos_ind[p];
        {  // conf gather: flat index over [B,9,16,16]
            int b = ind / 2304, r = ind % 2304;
            int c = r >> 8, r2 = r & 255;
            float cv = conf[(b * 256 + r2) * 9 + c];
            cls += softplus(-cv);
        }
        float off[4];
#pragma unroll
        for (int j = 0; j < 4; ++j) {  // reg.reshape(-1,4)[ind]: 4 consecutive flat elems of [B,36,16,16]
            int e = 4 * ind + j;
            int b = e / 9216, r = e % 9216;
            int c = r >> 8, r2 = r & 255;
            off[j] = reg[(b * 256 + r2) * 36 + c];
        }
        float ax1 = anc[4 * p], ay1 = anc[4 * p + 1], ax2 = anc[4 * p + 2], ay2 = anc[4 * p + 3];
        float acx = (ax1 + ax2) * 0.5f, acy = (ay1 + ay2) * 0.5f;
        float aw = ax2 - ax1, ah = ay2 - ay1;
        float pcx = acx + off[0] * aw, pcy = acy + off[1] * ah;
        float pw = aw * expf(off[2]), ph = ah * expf(off[3]);
        out[1 + 4 * p + 0] = pcx - pw * 0.5f;
        out[1 + 4 * p + 1] = pcy - ph * 0.5f;
        out[1 + 4 * p + 2] = pcx + pw * 0.5f;
        out[1 + 4 * p + 3] = pcy + ph * 0.5f;
        float gx1 = gt[4 * p], gy1 = gt[4 * p + 1], gx2 = gt[4 * p + 2], gy2 = gt[4 * p + 3];
        float gcx = (gx1 + gx2) * 0.5f, gcy = (gy1 + gy2) * 0.5f;
        float gw = gx2 - gx1, gh = gy2 - gy1;
        float tv[4];
        tv[0] = (gcx - acx) / aw;
        tv[1] = (gcy - acy) / ah;
        tv[2] = logf(gw / aw);
        tv[3] = logf(gh / ah);
#pragma unroll
        for (int j = 0; j < 4; ++j) {
            float d = off[j] - tv[j];
            float ad = fabsf(d);
            rloss += (ad < 1.f) ? 0.5f * d * d : ad - 0.5f;
        }
    }
    for (int q = t; q < NNEG; q += 256) {
        int ind = neg_ind[q];
        int b = ind / 2304, r = ind % 2304;
        int c = r >> 8, r2 = r & 255;
        float cv = conf[(b * 256 + r2) * 9 + c];
        cls += softplus(cv);
    }
    __shared__ float s1[256], s2[256];
    s1[t] = cls;
    s2[t] = rloss;
    __syncthreads();
    for (int s = 128; s > 0; s >>= 1) {
        if (t < s) {
            s1[t] += s1[t + s];
            s2[t] += s2[t + s];
        }
        __syncthreads();
    }
    if (t == 0) out[0] = (s1[0] + 5.f * s2[0]) / 16.f;
}

extern "C" void kernel_launch(void* const* d_in, const int* in_sizes, int n_in,
                              void* d_out, int out_size, void* d_ws, size_t ws_size,
                              hipStream_t stream) {
    const float* F   = (const float*)d_in[0];
    const float* anc = (const float*)d_in[1];
    const float* gt  = (const float*)d_in[2];
    const float* W1  = (const float*)d_in[3];
    const float* b1  = (const float*)d_in[4];
    const float* Wc  = (const float*)d_in[5];
    const float* bc  = (const float*)d_in[6];
    const float* Wr  = (const float*)d_in[7];
    const float* br  = (const float*)d_in[8];
    const int* pos_ind = (const int*)d_in[9];
    const int* neg_ind = (const int*)d_in[10];
    float* out = (float*)d_out;

    char* ws = (char*)d_ws;
    const size_t FP_BYTES   = (size_t)16 * 18 * 18 * CIN * 2;  // 21,233,664
    const size_t WT_BYTES   = (size_t)9 * HID * CIN * 2;       // 18,874,368
    const size_t CONF_BYTES = (size_t)4096 * 9 * 4;
    const size_t REG_BYTES  = (size_t)4096 * 36 * 4;
    const size_t PART_ONE   = (size_t)4096 * HID * 4;          // 8 MB per split

    int NS = 4;  // split-K factor; shrink if workspace is tight
    while (NS > 1 &&
           FP_BYTES + WT_BYTES + CONF_BYTES + REG_BYTES + (size_t)NS * PART_ONE > ws_size)
        NS >>= 1;
    int icLen = CIN / NS;

    ushort_t* Fp  = (ushort_t*)ws;
    ushort_t* Wt2 = (ushort_t*)(ws + FP_BYTES);
    float* Part   = (float*)(ws + FP_BYTES + WT_BYTES);
    float* conf   = (float*)(ws + FP_BYTES + WT_BYTES + (size_t)NS * PART_ONE);
    float* reg    = (float*)(ws + FP_BYTES + WT_BYTES + (size_t)NS * PART_ONE + CONF_BYTES);

    hipMemsetAsync(Fp, 0, FP_BYTES, stream);
    k_prep_fmap<<<256, 256, 0, stream>>>(F, Fp);
    k_prep_w<<<512, 256, 0, stream>>>(W1, Wt2);
    k_gemm<<<256 * NS, 256, 0, stream>>>(Fp, Wt2, Part, icLen);
    k_finish<<<1024, 256, 0, stream>>>(Part, NS, b1, Wc, bc, Wr, br, conf, reg);
    k_loss<<<1, 256, 0, stream>>>(conf, reg, pos_ind, neg_ind, anc, gt, out);
}

// Round 3
// 177.540 us; speedup vs baseline: 2.1912x; 1.0670x over previous
//
#include <hip/hip_runtime.h>
#include <hip/hip_bf16.h>
#include <stdint.h>

#define CIN 2048
#define HID 512
#define NPOS 2048
#define NNEG 2048

typedef __attribute__((ext_vector_type(8))) short s16x8;
typedef __attribute__((ext_vector_type(4))) short s16x4;
typedef __attribute__((ext_vector_type(4))) float f32x4;
typedef unsigned short ushort_t;

static __device__ __forceinline__ float bf2f(unsigned short u) {
    union { float f; unsigned int i; } v; v.i = ((unsigned int)u) << 16; return v.f;
}
static __device__ __forceinline__ unsigned short f2bf(float f) {
    union { float f; unsigned int i; } v; v.f = f;
    unsigned int r = v.i + 0x7FFF + ((v.i >> 16) & 1);  // RNE
    return (unsigned short)(r >> 16);
}

typedef __attribute__((address_space(1))) const void gvoid_t;
typedef __attribute__((address_space(3))) void lvoid_t;
static __device__ __forceinline__ void gload16(const void* g, void* l) {
    __builtin_amdgcn_global_load_lds((gvoid_t*)g, (lvoid_t*)l, 16, 0, 0);
}

// ---------------- pass 1: NCHW f32 -> padded NHWC bf16 ----------------
// Fp[b][Y][X][ic], Y,X in [0,18), interior at Y=y+1,X=x+1. Border pre-zeroed by memset.
__global__ __launch_bounds__(256) void k_prep_fmap(const float* __restrict__ F,
                                                   ushort_t* __restrict__ Fp) {
    int b = blockIdx.x >> 4;
    int y = blockIdx.x & 15;
    int t = threadIdx.x;
    __shared__ float tile[64][17];
    for (int ic0 = 0; ic0 < CIN; ic0 += 64) {
        {   // read 64 ci x 16 x, float4 per thread
            int ci = t >> 2, xg = t & 3;
            const float4 v = *(const float4*)&F[((size_t)(b * CIN + ic0 + ci) * 16 + y) * 16 + xg * 4];
            tile[ci][xg * 4 + 0] = v.x;
            tile[ci][xg * 4 + 1] = v.y;
            tile[ci][xg * 4 + 2] = v.z;
            tile[ci][xg * 4 + 3] = v.w;
        }
        __syncthreads();
        {   // write 16 x x 64 ci, 4 bf16 (8B) per thread
            int x = t >> 4, cig = t & 15;
            s16x4 o;
#pragma unroll
            for (int j = 0; j < 4; ++j) o[j] = (short)f2bf(tile[cig * 4 + j][x]);
            *(s16x4*)&Fp[((size_t)(b * 18 + y + 1) * 18 + (x + 1)) * CIN + ic0 + cig * 4] = o;
        }
        __syncthreads();
    }
}

// ---------------- pass 2: W1[oc][ic][3][3] f32 -> Wt2[k][oc][ic] bf16 ----------------
__global__ __launch_bounds__(256) void k_prep_w(const float* __restrict__ W1,
                                                ushort_t* __restrict__ Wt2) {
    int oc = blockIdx.x;
    int t = threadIdx.x;
    __shared__ float buf[512 * 9];
    for (int ic0 = 0; ic0 < CIN; ic0 += 512) {
        const float* src = W1 + ((size_t)oc * CIN + ic0) * 9;
        for (int i = t; i < 512 * 9; i += 256) buf[i] = src[i];
        __syncthreads();
        for (int s = t; s < 9 * 64; s += 256) {  // 16B store per (k, 8-ic group)
            int k = s >> 6, g = s & 63;
            s16x8 v;
#pragma unroll
            for (int j = 0; j < 8; ++j) v[j] = (short)f2bf(buf[(g * 8 + j) * 9 + k]);
            *(s16x8*)&Wt2[((size_t)(k * HID + oc)) * CIN + ic0 + g * 8] = v;
        }
        __syncthreads();
    }
}

// ---------------- pass 3: split-K implicit-GEMM conv -> Part[4][4096][512] f32 ------
#define BM 128
#define BN 128
#define BK 64
#define NSPLIT 4

__global__ __launch_bounds__(256, 2) void k_gemm(const ushort_t* __restrict__ Fp,
                                                 const ushort_t* __restrict__ Wt2,
                                                 float* __restrict__ Part, int icLen) {
    __shared__ __align__(16) ushort_t As[2][BM * BK];  // 2 x 16 KB
    __shared__ __align__(16) ushort_t Bs[2][BN * BK];  // 2 x 16 KB

    int bid = blockIdx.x;          // bid = rb*16 + split*4 + cb  (bid%8 pins XCD)
    int cb = bid & 3;
    int split = (bid >> 2) & 3;
    int rb = bid >> 4;
    int icBase = split * icLen;
    int m0 = rb * BM, oc0 = cb * BN;
    int t = threadIdx.x;
    int w = t >> 6, lane = t & 63;
    int wr = w >> 1, wc = w & 1;
    int hi = lane >> 4;

    f32x4 acc[4][4];
#pragma unroll
    for (int a = 0; a < 4; ++a)
#pragma unroll
        for (int b = 0; b < 4; ++b) acc[a][b] = (f32x4){0.f, 0.f, 0.f, 0.f};

    // staging bases; pre-swizzled global 16B segment (T2, both-sides rule #21)
    int Abase[4], Bbase[4];
#pragma unroll
    for (int i = 0; i < 4; ++i) {
        int li = i * 256 + t;
        int gr = li >> 3;                 // LDS row 0..127
        int sg = (li & 7) ^ (gr & 7);     // swizzled 16B segment
        int m = m0 + gr;
        int b = m >> 8, y = (m >> 4) & 15, x = m & 15;
        Abase[i] = ((b * 18 + y) * 18 + x) * CIN + sg * 8;
        Bbase[i] = (oc0 + gr) * CIN + sg * 8;
    }
    // swizzled ds_read element indices
    int aidx[4][2], bidx[4][2];
#pragma unroll
    for (int fm = 0; fm < 4; ++fm)
#pragma unroll
        for (int ks = 0; ks < 2; ++ks) {
            int r = wr * 64 + fm * 16 + (lane & 15);
            aidx[fm][ks] = r * BK + ((ks * 32 + hi * 8) ^ ((r & 7) << 3));
            int rB = wc * 64 + fm * 16 + (lane & 15);
            bidx[fm][ks] = rB * BK + ((ks * 32 + hi * 8) ^ ((rB & 7) << 3));
        }

    int nsteps = (icLen >> 6) * 9;  // kidx inner, ic-chunk outer

#define STAGE(BUF, STEP)                                                          \
    do {                                                                          \
        int kidx_ = (STEP) % 9;                                                   \
        int ic0_ = icBase + ((STEP) / 9) * BK;                                    \
        int ky_ = kidx_ / 3, kx_ = kidx_ - 3 * ky_;                               \
        int akoff_ = (ky_ * 18 + kx_) * CIN + ic0_;                               \
        int bkoff_ = kidx_ * HID * CIN + ic0_;                                    \
        _Pragma("unroll") for (int i_ = 0; i_ < 4; ++i_) {                        \
            gload16(Fp + Abase[i_] + akoff_, &As[BUF][(size_t)(i_ * 256 + t) * 8]); \
            gload16(Wt2 + Bbase[i_] + bkoff_, &Bs[BUF][(size_t)(i_ * 256 + t) * 8]); \
        }                                                                         \
    } while (0)

    STAGE(0, 0);
    __syncthreads();
    int cur = 0;
#pragma unroll 1
    for (int step = 0; step < nsteps; ++step) {
        if (step + 1 < nsteps) STAGE(cur ^ 1, step + 1);

        s16x8 af[4][2], bf[4][2];
#pragma unroll
        for (int ks = 0; ks < 2; ++ks) {
#pragma unroll
            for (int fm = 0; fm < 4; ++fm) af[fm][ks] = *(const s16x8*)&As[cur][aidx[fm][ks]];
#pragma unroll
            for (int fn = 0; fn < 4; ++fn) bf[fn][ks] = *(const s16x8*)&Bs[cur][bidx[fn][ks]];
        }
#pragma unroll
        for (int fm = 0; fm < 4; ++fm)
#pragma unroll
            for (int fn = 0; fn < 4; ++fn)
#pragma unroll
                for (int ks = 0; ks < 2; ++ks)
                    acc[fm][fn] = __builtin_amdgcn_mfma_f32_16x16x32_bf16(
                        af[fm][ks], bf[fn][ks], acc[fm][fn], 0, 0, 0);
        __syncthreads();   // drains vmcnt(0): next tile staged; cur buffer free
        cur ^= 1;
    }
#undef STAGE

    // epilogue: store f32 partials
#pragma unroll
    for (int fm = 0; fm < 4; ++fm)
#pragma unroll
        for (int fn = 0; fn < 4; ++fn)
#pragma unroll
            for (int r = 0; r < 4; ++r) {
                int gm = m0 + wr * 64 + fm * 16 + hi * 4 + r;
                int gn = oc0 + wc * 64 + fn * 16 + (lane & 15);
                Part[((size_t)split * 4096 + gm) * HID + gn] = acc[fm][fn][r];
            }
}

// ---------------- pass 4: reduce splits + bias + ReLU + 1x1 heads -------------------
__global__ __launch_bounds__(256) void k_finish(const float* __restrict__ Part, int ns,
                                                const float* __restrict__ b1,
                                                const float* __restrict__ Wc,
                                                const float* __restrict__ bc,
                                                const float* __restrict__ Wr,
                                                const float* __restrict__ br,
                                                float* __restrict__ conf,
                                                float* __restrict__ reg) {
    int w = threadIdx.x >> 6, lane = threadIdx.x & 63;
    int m = blockIdx.x * 4 + w;
    float ov[8];
#pragma unroll
    for (int j = 0; j < 8; ++j) ov[j] = 0.f;
    for (int s = 0; s < ns; ++s) {
        const float4* p = (const float4*)&Part[((size_t)s * 4096 + m) * HID + lane * 8];
        float4 v0 = p[0], v1 = p[1];
        ov[0] += v0.x; ov[1] += v0.y; ov[2] += v0.z; ov[3] += v0.w;
        ov[4] += v1.x; ov[5] += v1.y; ov[6] += v1.z; ov[7] += v1.w;
    }
#pragma unroll
    for (int j = 0; j < 8; ++j) ov[j] = fmaxf(ov[j] + b1[lane * 8 + j], 0.f);
#pragma unroll 1
    for (int o = 0; o < 45; ++o) {
        const float* Wrow = (o < 9) ? (Wc + o * HID) : (Wr + (size_t)(o - 9) * HID);
        float p = 0.f;
#pragma unroll
        for (int j = 0; j < 8; ++j) p += ov[j] * Wrow[lane * 8 + j];
#pragma unroll
        for (int s = 32; s > 0; s >>= 1) p += __shfl_xor(p, s);
        if (lane == 0) {
            if (o < 9)
                conf[m * 9 + o] = p + bc[o];
            else
                reg[m * 36 + (o - 9)] = p + br[o - 9];
        }
    }
}

// ---------------- pass 5: gathers + proposals + losses ------------------------------
static __device__ __forceinline__ float softplus(float x) {
    return log1pf(expf(-fabsf(x))) + fmaxf(x, 0.f);
}

__global__ __launch_bounds__(256) void k_loss(const float* __restrict__ conf,
                                              const float* __restrict__ reg,
                                              const int* __restrict__ pos_ind,
                                              const int* __restrict__ neg_ind,
                                              const float* __restrict__ anc,
                                              const float* __restrict__ gt,
                                              float* __restrict__ out) {
    int t = threadIdx.x;
    float cls = 0.f, rloss = 0.f;
    for (int p = t; p < NPOS; p += 256) {
        int ind = pos_ind[p];
        {  // conf gather: flat index over [B,9,16,16]
            int b = ind / 2304, r = ind % 2304;
            int c = r >> 8, r2 = r & 255;
            float cv = conf[(b * 256 + r2) * 9 + c];
            cls += softplus(-cv);
        }
        float off[4];
#pragma unroll
        for (int j = 0; j < 4; ++j) {  // reg.reshape(-1,4)[ind]
            int e = 4 * ind + j;
            int b = e / 9216, r = e % 9216;
            int c = r >> 8, r2 = r & 255;
            off[j] = reg[(b * 256 + r2) * 36 + c];
        }
        float ax1 = anc[4 * p], ay1 = anc[4 * p + 1], ax2 = anc[4 * p + 2], ay2 = anc[4 * p + 3];
        float acx = (ax1 + ax2) * 0.5f, acy = (ay1 + ay2) * 0.5f;
        float aw = ax2 - ax1, ah = ay2 - ay1;
        float pcx = acx + off[0] * aw, pcy = acy + off[1] * ah;
        float pw = aw * expf(off[2]), ph = ah * expf(off[3]);
        out[1 + 4 * p + 0] = pcx - pw * 0.5f;
        out[1 + 4 * p + 1] = pcy - ph * 0.5f;
        out[1 + 4 * p + 2] = pcx + pw * 0.5f;
        out[1 + 4 * p + 3] = pcy + ph * 0.5f;
        float gx1 = gt[4 * p], gy1 = gt[4 * p + 1], gx2 = gt[4 * p + 2], gy2 = gt[4 * p + 3];
        float gcx = (gx1 + gx2) * 0.5f, gcy = (gy1 + gy2) * 0.5f;
        float gw = gx2 - gx1, gh = gy2 - gy1;
        float tv[4];
        tv[0] = (gcx - acx) / aw;
        tv[1] = (gcy - acy) / ah;
        tv[2] = logf(gw / aw);
        tv[3] = logf(gh / ah);
#pragma unroll
        for (int j = 0; j < 4; ++j) {
            float d = off[j] - tv[j];
            float ad = fabsf(d);
            rloss += (ad < 1.f) ? 0.5f * d * d : ad - 0.5f;
        }
    }
    for (int q = t; q < NNEG; q += 256) {
        int ind = neg_ind[q];
        int b = ind / 2304, r = ind % 2304;
        int c = r >> 8, r2 = r & 255;
        float cv = conf[(b * 256 + r2) * 9 + c];
        cls += softplus(cv);
    }
    __shared__ float s1[256], s2[256];
    s1[t] = cls;
    s2[t] = rloss;
    __syncthreads();
    for (int s = 128; s > 0; s >>= 1) {
        if (t < s) {
            s1[t] += s1[t + s];
            s2[t] += s2[t + s];
        }
        __syncthreads();
    }
    if (t == 0) out[0] = (s1[0] + 5.f * s2[0]) / 16.f;
}

extern "C" void kernel_launch(void* const* d_in, const int* in_sizes, int n_in,
                              void* d_out, int out_size, void* d_ws, size_t ws_size,
                              hipStream_t stream) {
    const float* F   = (const float*)d_in[0];
    const float* anc = (const float*)d_in[1];
    const float* gt  = (const float*)d_in[2];
    const float* W1  = (const float*)d_in[3];
    const float* b1  = (const float*)d_in[4];
    const float* Wc  = (const float*)d_in[5];
    const float* bc  = (const float*)d_in[6];
    const float* Wr  = (const float*)d_in[7];
    const float* br  = (const float*)d_in[8];
    const int* pos_ind = (const int*)d_in[9];
    const int* neg_ind = (const int*)d_in[10];
    float* out = (float*)d_out;

    char* ws = (char*)d_ws;
    const size_t FP_BYTES   = (size_t)16 * 18 * 18 * CIN * 2;  // 21,233,664
    const size_t WT_BYTES   = (size_t)9 * HID * CIN * 2;       // 18,874,368
    const size_t CONF_BYTES = (size_t)4096 * 9 * 4;
    const size_t PART_ONE   = (size_t)4096 * HID * 4;          // 8 MB per split

    int icLen = CIN / NSPLIT;  // 512

    ushort_t* Fp  = (ushort_t*)ws;
    ushort_t* Wt2 = (ushort_t*)(ws + FP_BYTES);
    float* Part   = (float*)(ws + FP_BYTES + WT_BYTES);
    float* conf   = (float*)(ws + FP_BYTES + WT_BYTES + (size_t)NSPLIT * PART_ONE);
    float* reg    = (float*)(ws + FP_BYTES + WT_BYTES + (size_t)NSPLIT * PART_ONE + CONF_BYTES);

    hipMemsetAsync(Fp, 0, FP_BYTES, stream);
    k_prep_fmap<<<256, 256, 0, stream>>>(F, Fp);
    k_prep_w<<<512, 256, 0, stream>>>(W1, Wt2);
    k_gemm<<<(4096 / BM) * (HID / BN) * NSPLIT, 256, 0, stream>>>(Fp, Wt2, Part, icLen);
    k_finish<<<1024, 256, 0, stream>>>(Part, NSPLIT, b1, Wc, bc, Wr, br, conf, reg);
    k_loss<<<1, 256, 0, stream>>>(conf, reg, pos_ind, neg_ind, anc, gt, out);
}

// Round 5
// 147.083 us; speedup vs baseline: 2.6449x; 1.2071x over previous
//
#include <hip/hip_runtime.h>
#include <hip/hip_bf16.h>
#include <stdint.h>

#define CIN 2048
#define HID 512
#define NPOS 2048
#define NNEG 2048

#define BM 256
#define BN 128
#define BK 64
#define NSPLIT 4
#define A_ELEMS (BM * BK)  // 16384
#define B_ELEMS (BN * BK)  // 8192

typedef __attribute__((ext_vector_type(8))) short s16x8;
typedef __attribute__((ext_vector_type(4))) short s16x4;
typedef __attribute__((ext_vector_type(4))) float f32x4;
typedef unsigned short ushort_t;

static __device__ __forceinline__ unsigned short f2bf(float f) {
    union { float f; unsigned int i; } v; v.f = f;
    unsigned int r = v.i + 0x7FFF + ((v.i >> 16) & 1);  // RNE
    return (unsigned short)(r >> 16);
}

typedef __attribute__((address_space(1))) const void gvoid_t;
typedef __attribute__((address_space(3))) void lvoid_t;
static __device__ __forceinline__ void gload16(const void* g, void* l) {
    __builtin_amdgcn_global_load_lds((gvoid_t*)g, (lvoid_t*)l, 16, 0, 0);
}

// ============ pass 1 (fused): NCHW->NHWC bf16, W transpose, border zero ============
// Fp[b][Y][X][ic], Y,X in [0,18); interior at Y=y+1,X=x+1; border zeroed by tail blocks.
__global__ __launch_bounds__(256) void k_prep(const float* __restrict__ F,
                                              const float* __restrict__ W1,
                                              ushort_t* __restrict__ Fp,
                                              ushort_t* __restrict__ Wt2) {
    __shared__ float tile[64][17];
    __shared__ float buf[512 * 9];
    int bid = blockIdx.x;
    int t = threadIdx.x;
    if (bid < 256) {
        int b = bid >> 4, y = bid & 15;
        for (int ic0 = 0; ic0 < CIN; ic0 += 64) {
            {   // read 64 ci x 16 x, float4 per thread
                int ci = t >> 2, xg = t & 3;
                const float4 v = *(const float4*)&F[((size_t)(b * CIN + ic0 + ci) * 16 + y) * 16 + xg * 4];
                tile[ci][xg * 4 + 0] = v.x;
                tile[ci][xg * 4 + 1] = v.y;
                tile[ci][xg * 4 + 2] = v.z;
                tile[ci][xg * 4 + 3] = v.w;
            }
            __syncthreads();
            {   // write 16 x x 64 ci, 4 bf16 (8B) per thread
                int x = t >> 4, cig = t & 15;
                s16x4 o;
#pragma unroll
                for (int j = 0; j < 4; ++j) o[j] = (short)f2bf(tile[cig * 4 + j][x]);
                *(s16x4*)&Fp[((size_t)(b * 18 + y + 1) * 18 + (x + 1)) * CIN + ic0 + cig * 4] = o;
            }
            __syncthreads();
        }
    } else if (bid < 768) {
        int oc = bid - 256;
        for (int ic0 = 0; ic0 < CIN; ic0 += 512) {
            const float* src = W1 + ((size_t)oc * CIN + ic0) * 9;
            for (int i = t; i < 512 * 9; i += 256) buf[i] = src[i];
            __syncthreads();
            for (int s = t; s < 9 * 64; s += 256) {  // 16B store per (k, 8-ic group)
                int k = s >> 6, g = s & 63;
                s16x8 v;
#pragma unroll
                for (int j = 0; j < 8; ++j) v[j] = (short)f2bf(buf[(g * 8 + j) * 9 + k]);
                *(s16x8*)&Wt2[((size_t)(k * HID + oc)) * CIN + ic0 + g * 8] = v;
            }
            __syncthreads();
        }
    } else {
        // zero the 68 border cells per image (16 b x 68 cells x 256 segs of 8 ch)
        const s16x8 z = {0, 0, 0, 0, 0, 0, 0, 0};
        for (int idx = (bid - 768) * 256 + t; idx < 16 * 68 * 256; idx += 64 * 256) {
            int seg = idx & 255;
            int cell = (idx >> 8) % 68;
            int b = idx / (68 * 256);
            int Y, X;
            if (cell < 18)      { Y = 0;         X = cell; }
            else if (cell < 36) { Y = 17;        X = cell - 18; }
            else if (cell < 52) { Y = cell - 35; X = 0; }
            else                { Y = cell - 51; X = 17; }
            *(s16x8*)&Fp[((size_t)(b * 18 + Y) * 18 + X) * CIN + seg * 8] = z;
        }
    }
}

// ============ pass 2: pipelined split-K implicit-GEMM -> Part[4][4096][512] ============
// 512 thr = 8 waves (4M x 2N), wave tile 64x64. 3-buffer LDS (144 KB dynamic).
// Depth-2 prefetch with counted vmcnt; the tile-ready wait is vmcnt(N)+s_barrier at
// END of step (cross-wave safe: after the barrier, ALL waves' DMAs for t+1 landed).
__global__ __launch_bounds__(512, 2) void k_gemm(const ushort_t* __restrict__ Fp,
                                                 const ushort_t* __restrict__ Wt2,
                                                 float* __restrict__ Part) {
    extern __shared__ ushort_t ldsbuf[];
    ushort_t* As = ldsbuf;                 // [3][A_ELEMS]
    ushort_t* Bs = ldsbuf + 3 * A_ELEMS;   // [3][B_ELEMS]

    int bid = blockIdx.x;          // bid = rb*16 + pair; XCD = bid%8 = pair%8
    int pair = bid & 15, rb = bid >> 4;
    int split = pair >> 2, cb = pair & 3;
    int icBase = split * (CIN / NSPLIT);
    int m0 = rb * BM, oc0 = cb * BN;
    int t = threadIdx.x;
    int wid = t >> 6, lane = t & 63;
    int wr = wid >> 1, wn = wid & 1;
    int hi = lane >> 4, lo = lane & 15;

    f32x4 acc[4][4];
#pragma unroll
    for (int a = 0; a < 4; ++a)
#pragma unroll
        for (int b = 0; b < 4; ++b) acc[a][b] = (f32x4){0.f, 0.f, 0.f, 0.f};

    // staging bases (pre-swizzled global 16B segment; LDS dest linear — rule #21)
    int Abase[4], Bbase[2];
#pragma unroll
    for (int j = 0; j < 4; ++j) {
        int li = j * 512 + t;
        int row = li >> 3;
        int sg = (li & 7) ^ (row & 7);
        int m = m0 + row;
        int b = m >> 8, y = (m >> 4) & 15, x = m & 15;
        Abase[j] = ((b * 18 + y) * 18 + x) * CIN + sg * 8;
    }
#pragma unroll
    for (int j = 0; j < 2; ++j) {
        int li = j * 512 + t;
        int row = li >> 3;
        int sg = (li & 7) ^ (row & 7);
        Bbase[j] = (oc0 + row) * CIN + sg * 8;
    }
    // swizzled ds_read element indices
    int aidx[4][2], bidx[4][2];
#pragma unroll
    for (int fm = 0; fm < 4; ++fm)
#pragma unroll
        for (int ks = 0; ks < 2; ++ks) {
            int r = wr * 64 + fm * 16 + lo;
            aidx[fm][ks] = r * BK + ((ks * 32 + hi * 8) ^ ((r & 7) << 3));
            int rB = wn * 64 + fm * 16 + lo;
            bidx[fm][ks] = rB * BK + ((ks * 32 + hi * 8) ^ ((rB & 7) << 3));
        }

    const int nsteps = (CIN / NSPLIT / BK) * 9;  // 72; kidx inner, ic-chunk outer

#define STAGE_A(BUF, S)                                                              \
    do {                                                                             \
        int kidx_ = (S) % 9, icc_ = (S) / 9;                                         \
        int ak_ = ((kidx_ / 3) * 18 + (kidx_ - 3 * (kidx_ / 3))) * CIN + icBase + icc_ * BK; \
        ushort_t* dA_ = As + (BUF) * A_ELEMS;                                        \
        _Pragma("unroll") for (int j_ = 0; j_ < 4; ++j_)                             \
            gload16(Fp + Abase[j_] + ak_, dA_ + (size_t)(j_ * 512 + t) * 8);         \
    } while (0)
#define STAGE_B(BUF, S)                                                              \
    do {                                                                             \
        int kidx_ = (S) % 9, icc_ = (S) / 9;                                         \
        int bk_ = kidx_ * HID * CIN + icBase + icc_ * BK;                            \
        ushort_t* dB_ = Bs + (BUF) * B_ELEMS;                                        \
        _Pragma("unroll") for (int j_ = 0; j_ < 2; ++j_)                             \
            gload16(Wt2 + Bbase[j_] + bk_, dB_ + (size_t)(j_ * 512 + t) * 8);        \
    } while (0)

    // prologue: tiles 0 and 1 in flight (12 loads/wave); ensure tile 0 staged by ALL
    STAGE_A(0, 0); STAGE_B(0, 0);
    STAGE_A(1, 1); STAGE_B(1, 1);
    asm volatile("s_waitcnt vmcnt(6)" ::: "memory");   // own tile-0 loads done
    __builtin_amdgcn_s_barrier();                       // everyone's tile-0 loads done
    __builtin_amdgcn_sched_barrier(0);

    int bi = 0;
#pragma unroll 1
    for (int step = 0; step < nsteps; ++step) {
        const ushort_t* cA = As + bi * A_ELEMS;
        const ushort_t* cB = Bs + bi * B_ELEMS;
        int b2 = (bi >= 1) ? bi - 1 : 2;  // (bi+2)%3
        // ---- phase 0: read A + B-half0 of tile step; stage A(step+2)
        s16x8 af[4][2], bf0[2][2];
#pragma unroll
        for (int ks = 0; ks < 2; ++ks) {
#pragma unroll
            for (int fm = 0; fm < 4; ++fm) af[fm][ks] = *(const s16x8*)&cA[aidx[fm][ks]];
#pragma unroll
            for (int fn = 0; fn < 2; ++fn) bf0[fn][ks] = *(const s16x8*)&cB[bidx[fn][ks]];
        }
        if (step + 2 < nsteps) STAGE_A(b2, step + 2);
        asm volatile("s_waitcnt lgkmcnt(0)" ::: "memory");
        __builtin_amdgcn_sched_barrier(0);
        __builtin_amdgcn_s_setprio(1);
#pragma unroll
        for (int fm = 0; fm < 4; ++fm)
#pragma unroll
            for (int fn = 0; fn < 2; ++fn)
#pragma unroll
                for (int ks = 0; ks < 2; ++ks)
                    acc[fm][fn] = __builtin_amdgcn_mfma_f32_16x16x32_bf16(
                        af[fm][ks], bf0[fn][ks], acc[fm][fn], 0, 0, 0);
        __builtin_amdgcn_s_setprio(0);
        // ---- phase 1: read B-half1; stage B(step+2)
        s16x8 bf1[2][2];
#pragma unroll
        for (int ks = 0; ks < 2; ++ks)
#pragma unroll
            for (int fn = 0; fn < 2; ++fn) bf1[fn][ks] = *(const s16x8*)&cB[bidx[2 + fn][ks]];
        if (step + 2 < nsteps) STAGE_B(b2, step + 2);
        asm volatile("s_waitcnt lgkmcnt(0)" ::: "memory");
        __builtin_amdgcn_sched_barrier(0);
        __builtin_amdgcn_s_setprio(1);
#pragma unroll
        for (int fm = 0; fm < 4; ++fm)
#pragma unroll
            for (int fn = 0; fn < 2; ++fn)
#pragma unroll
                for (int ks = 0; ks < 2; ++ks)
                    acc[fm][2 + fn] = __builtin_amdgcn_mfma_f32_16x16x32_bf16(
                        af[fm][ks], bf1[fn][ks], acc[fm][2 + fn], 0, 0, 0);
        __builtin_amdgcn_s_setprio(0);
        // ---- end of step: tile step+1 readiness (counted, cross-wave via barrier)
        if (step + 2 < nsteps) {
            asm volatile("s_waitcnt vmcnt(6)" ::: "memory");   // tile step+1 done (own)
            __builtin_amdgcn_s_barrier();                       // ... and everyone's
            __builtin_amdgcn_sched_barrier(0);
        } else if (step + 1 < nsteps) {
            asm volatile("s_waitcnt vmcnt(0)" ::: "memory");
            __builtin_amdgcn_s_barrier();
            __builtin_amdgcn_sched_barrier(0);
        }
        bi = (bi == 2) ? 0 : bi + 1;
    }
#undef STAGE_A
#undef STAGE_B

    // epilogue: store f32 partials
#pragma unroll
    for (int fm = 0; fm < 4; ++fm)
#pragma unroll
        for (int fn = 0; fn < 4; ++fn)
#pragma unroll
            for (int r = 0; r < 4; ++r) {
                int gm = m0 + wr * 64 + fm * 16 + hi * 4 + r;
                int gn = oc0 + wn * 64 + fn * 16 + lo;
                Part[((size_t)split * 4096 + gm) * HID + gn] = acc[fm][fn][r];
            }
}

// ============ pass 3: reduce splits + bias + ReLU -> MFMA 1x1 heads ============
// grid 64 blocks x 64 rows; 4 waves, wave tile 16 rows x 48 head-cols.
__global__ __launch_bounds__(256) void k_heads(const float* __restrict__ Part,
                                               const float* __restrict__ b1,
                                               const float* __restrict__ Wc,
                                               const float* __restrict__ bc,
                                               const float* __restrict__ Wr,
                                               const float* __restrict__ br,
                                               float* __restrict__ conf,
                                               float* __restrict__ reg) {
    __shared__ __align__(16) ushort_t Ah[64 * 64];  // 8 KB (swizzled)
    __shared__ __align__(16) ushort_t Wh[48 * 64];  // 6 KB (swizzled)
    int t = threadIdx.x;
    int wid = t >> 6, lane = t & 63;
    int hi = lane >> 4, lo = lane & 15;
    int row0 = blockIdx.x * 64;

    f32x4 acc[3];
#pragma unroll
    for (int fn = 0; fn < 3; ++fn) acc[fn] = (f32x4){0.f, 0.f, 0.f, 0.f};

#pragma unroll 1
    for (int kc = 0; kc < HID / 64; ++kc) {
        int k0 = kc * 64;
        // stage hidden tile: sum splits + bias + relu -> bf16 swizzled
#pragma unroll
        for (int g = 0; g < 4; ++g) {
            int fid = g * 256 + t;           // [0,1024)
            int r = fid >> 4, c4 = (fid & 15) * 4;
            float4 s = {0.f, 0.f, 0.f, 0.f};
#pragma unroll
            for (int sp = 0; sp < NSPLIT; ++sp) {
                const float4 v = *(const float4*)&Part[((size_t)sp * 4096 + row0 + r) * HID + k0 + c4];
                s.x += v.x; s.y += v.y; s.z += v.z; s.w += v.w;
            }
            s.x = fmaxf(s.x + b1[k0 + c4 + 0], 0.f);
            s.y = fmaxf(s.y + b1[k0 + c4 + 1], 0.f);
            s.z = fmaxf(s.z + b1[k0 + c4 + 2], 0.f);
            s.w = fmaxf(s.w + b1[k0 + c4 + 3], 0.f);
            s16x4 o = {(short)f2bf(s.x), (short)f2bf(s.y), (short)f2bf(s.z), (short)f2bf(s.w)};
            int phys = r * 64 + ((((c4 >> 3) ^ (r & 7)) << 3) | (c4 & 7));
            *(s16x4*)&Ah[phys] = o;
        }
        // stage head weights (rows 0-8: Wc, 9-44: Wr, 45-47: zero)
#pragma unroll
        for (int i = 0; i < 2; ++i) {
            int sid = i * 256 + t;
            if (sid < 384) {
                int o = sid >> 3, sg = sid & 7;
                s16x8 v;
#pragma unroll
                for (int j = 0; j < 8; ++j) {
                    float w = 0.f;
                    if (o < 9) w = Wc[o * HID + k0 + sg * 8 + j];
                    else if (o < 45) w = Wr[(size_t)(o - 9) * HID + k0 + sg * 8 + j];
                    v[j] = (short)f2bf(w);
                }
                *(s16x8*)&Wh[o * 64 + ((sg ^ (o & 7)) << 3)] = v;
            }
        }
        __syncthreads();
        int rA = wid * 16 + lo;
        s16x8 a_[2];
#pragma unroll
        for (int ks = 0; ks < 2; ++ks)
            a_[ks] = *(const s16x8*)&Ah[rA * 64 + ((ks * 32 + hi * 8) ^ ((rA & 7) << 3))];
#pragma unroll
        for (int fn = 0; fn < 3; ++fn) {
            int rB = fn * 16 + lo;
#pragma unroll
            for (int ks = 0; ks < 2; ++ks) {
                s16x8 b_ = *(const s16x8*)&Wh[rB * 64 + ((ks * 32 + hi * 8) ^ ((rB & 7) << 3))];
                acc[fn] = __builtin_amdgcn_mfma_f32_16x16x32_bf16(a_[ks], b_, acc[fn], 0, 0, 0);
            }
        }
        __syncthreads();
    }
    // write conf/reg with head bias
#pragma unroll
    for (int fn = 0; fn < 3; ++fn)
#pragma unroll
        for (int r = 0; r < 4; ++r) {
            int gm = row0 + wid * 16 + hi * 4 + r;
            int o = fn * 16 + lo;
            float v = acc[fn][r];
            if (o < 9) conf[gm * 9 + o] = v + bc[o];
            else if (o < 45) reg[gm * 36 + (o - 9)] = v + br[o - 9];
        }
}

// ============ pass 4: gathers + proposals + losses ============
static __device__ __forceinline__ float softplus(float x) {
    return log1pf(expf(-fabsf(x))) + fmaxf(x, 0.f);
}

__global__ __launch_bounds__(256) void k_loss(const float* __restrict__ conf,
                                              const float* __restrict__ reg,
                                              const int* __restrict__ pos_ind,
                                              const int* __restrict__ neg_ind,
                                              const float* __restrict__ anc,
                                              const float* __restrict__ gt,
                                              float* __restrict__ out) {
    int t = threadIdx.x;
    float cls = 0.f, rloss = 0.f;
    for (int p = t; p < NPOS; p += 256) {
        int ind = pos_ind[p];
        {  // conf gather: flat index over [B,9,16,16]
            int b = ind / 2304, r = ind % 2304;
            int c = r >> 8, r2 = r & 255;
            float cv = conf[(b * 256 + r2) * 9 + c];
            cls += softplus(-cv);
        }
        float off[4];
#pragma unroll
        for (int j = 0; j < 4; ++j) {  // reg.reshape(-1,4)[ind]
            int e = 4 * ind + j;
            int b = e / 9216, r = e % 9216;
            int c = r >> 8, r2 = r & 255;
            off[j] = reg[(b * 256 + r2) * 36 + c];
        }
        float ax1 = anc[4 * p], ay1 = anc[4 * p + 1], ax2 = anc[4 * p + 2], ay2 = anc[4 * p + 3];
        float acx = (ax1 + ax2) * 0.5f, acy = (ay1 + ay2) * 0.5f;
        float aw = ax2 - ax1, ah = ay2 - ay1;
        float pcx = acx + off[0] * aw, pcy = acy + off[1] * ah;
        float pw = aw * expf(off[2]), ph = ah * expf(off[3]);
        out[1 + 4 * p + 0] = pcx - pw * 0.5f;
        out[1 + 4 * p + 1] = pcy - ph * 0.5f;
        out[1 + 4 * p + 2] = pcx + pw * 0.5f;
        out[1 + 4 * p + 3] = pcy + ph * 0.5f;
        float gx1 = gt[4 * p], gy1 = gt[4 * p + 1], gx2 = gt[4 * p + 2], gy2 = gt[4 * p + 3];
        float gcx = (gx1 + gx2) * 0.5f, gcy = (gy1 + gy2) * 0.5f;
        float gw = gx2 - gx1, gh = gy2 - gy1;
        float tv[4];
        tv[0] = (gcx - acx) / aw;
        tv[1] = (gcy - acy) / ah;
        tv[2] = logf(gw / aw);
        tv[3] = logf(gh / ah);
#pragma unroll
        for (int j = 0; j < 4; ++j) {
            float d = off[j] - tv[j];
            float ad = fabsf(d);
            rloss += (ad < 1.f) ? 0.5f * d * d : ad - 0.5f;
        }
    }
    for (int q = t; q < NNEG; q += 256) {
        int ind = neg_ind[q];
        int b = ind / 2304, r = ind % 2304;
        int c = r >> 8, r2 = r & 255;
        float cv = conf[(b * 256 + r2) * 9 + c];
        cls += softplus(cv);
    }
    __shared__ float s1[256], s2[256];
    s1[t] = cls;
    s2[t] = rloss;
    __syncthreads();
    for (int s = 128; s > 0; s >>= 1) {
        if (t < s) {
            s1[t] += s1[t + s];
            s2[t] += s2[t + s];
        }
        __syncthreads();
    }
    if (t == 0) out[0] = (s1[0] + 5.f * s2[0]) / 16.f;
}

extern "C" void kernel_launch(void* const* d_in, const int* in_sizes, int n_in,
                              void* d_out, int out_size, void* d_ws, size_t ws_size,
                              hipStream_t stream) {
    const float* F   = (const float*)d_in[0];
    const float* anc = (const float*)d_in[1];
    const float* gt  = (const float*)d_in[2];
    const float* W1  = (const float*)d_in[3];
    const float* b1  = (const float*)d_in[4];
    const float* Wc  = (const float*)d_in[5];
    const float* bc  = (const float*)d_in[6];
    const float* Wr  = (const float*)d_in[7];
    const float* br  = (const float*)d_in[8];
    const int* pos_ind = (const int*)d_in[9];
    const int* neg_ind = (const int*)d_in[10];
    float* out = (float*)d_out;

    char* ws = (char*)d_ws;
    const size_t FP_BYTES   = (size_t)16 * 18 * 18 * CIN * 2;  // 21,233,664
    const size_t WT_BYTES   = (size_t)9 * HID * CIN * 2;       // 18,874,368
    const size_t PART_ONE   = (size_t)4096 * HID * 4;          // 8 MB per split
    const size_t CONF_BYTES = (size_t)4096 * 9 * 4;

    ushort_t* Fp  = (ushort_t*)ws;
    ushort_t* Wt2 = (ushort_t*)(ws + FP_BYTES);
    float* Part   = (float*)(ws + FP_BYTES + WT_BYTES);
    float* conf   = (float*)(ws + FP_BYTES + WT_BYTES + (size_t)NSPLIT * PART_ONE);
    float* reg    = (float*)(ws + FP_BYTES + WT_BYTES + (size_t)NSPLIT * PART_ONE + CONF_BYTES);

    const int GEMM_LDS = 3 * (A_ELEMS + B_ELEMS) * 2;  // 147456
    hipFuncSetAttribute((const void*)k_gemm, hipFuncAttributeMaxDynamicSharedMemorySize, GEMM_LDS);

    k_prep<<<832, 256, 0, stream>>>(F, W1, Fp, Wt2);
    k_gemm<<<(4096 / BM) * (HID / BN) * NSPLIT, 512, GEMM_LDS, stream>>>(Fp, Wt2, Part);
    k_heads<<<64, 256, 0, stream>>>(Part, b1, Wc, bc, Wr, br, conf, reg);
    k_loss<<<1, 256, 0, stream>>>(conf, reg, pos_ind, neg_ind, anc, gt, out);
}

// Round 6
// 130.787 us; speedup vs baseline: 2.9745x; 1.1246x over previous
//
#include <hip/hip_runtime.h>
#include <hip/hip_bf16.h>
#include <stdint.h>

#define CIN 2048
#define HID 512
#define NPOS 2048
#define NNEG 2048

#define BM 256
#define BN 128
#define BK 64
#define NSPLIT 4
#define A_ELEMS (BM * BK)  // 16384
#define B_ELEMS (BN * BK)  // 8192

typedef __attribute__((ext_vector_type(8))) short s16x8;
typedef __attribute__((ext_vector_type(4))) short s16x4;
typedef __attribute__((ext_vector_type(4))) float f32x4;
typedef unsigned short ushort_t;

static __device__ __forceinline__ unsigned short f2bf(float f) {
    union { float f; unsigned int i; } v; v.f = f;
    unsigned int r = v.i + 0x7FFF + ((v.i >> 16) & 1);  // RNE
    return (unsigned short)(r >> 16);
}

typedef __attribute__((address_space(1))) const void gvoid_t;
typedef __attribute__((address_space(3))) void lvoid_t;
static __device__ __forceinline__ void gload16(const void* g, void* l) {
    __builtin_amdgcn_global_load_lds((gvoid_t*)g, (lvoid_t*)l, 16, 0, 0);
}

// ============ pass 1 (fused): NCHW->NHWC bf16, W transpose, border zero ============
__global__ __launch_bounds__(256) void k_prep(const float* __restrict__ F,
                                              const float* __restrict__ W1,
                                              ushort_t* __restrict__ Fp,
                                              ushort_t* __restrict__ Wt2) {
    __shared__ float tile[64][17];
    __shared__ float buf[512 * 9];
    int bid = blockIdx.x;
    int t = threadIdx.x;
    if (bid < 256) {
        int b = bid >> 4, y = bid & 15;
        for (int ic0 = 0; ic0 < CIN; ic0 += 64) {
            {   // read 64 ci x 16 x, float4 per thread
                int ci = t >> 2, xg = t & 3;
                const float4 v = *(const float4*)&F[((size_t)(b * CIN + ic0 + ci) * 16 + y) * 16 + xg * 4];
                tile[ci][xg * 4 + 0] = v.x;
                tile[ci][xg * 4 + 1] = v.y;
                tile[ci][xg * 4 + 2] = v.z;
                tile[ci][xg * 4 + 3] = v.w;
            }
            __syncthreads();
            {   // write 16 x x 64 ci, 4 bf16 (8B) per thread
                int x = t >> 4, cig = t & 15;
                s16x4 o;
#pragma unroll
                for (int j = 0; j < 4; ++j) o[j] = (short)f2bf(tile[cig * 4 + j][x]);
                *(s16x4*)&Fp[((size_t)(b * 18 + y + 1) * 18 + (x + 1)) * CIN + ic0 + cig * 4] = o;
            }
            __syncthreads();
        }
    } else if (bid < 768) {
        int oc = bid - 256;
        for (int ic0 = 0; ic0 < CIN; ic0 += 512) {
            const float* src = W1 + ((size_t)oc * CIN + ic0) * 9;
            for (int i = t; i < 512 * 9; i += 256) buf[i] = src[i];
            __syncthreads();
            for (int s = t; s < 9 * 64; s += 256) {  // 16B store per (k, 8-ic group)
                int k = s >> 6, g = s & 63;
                s16x8 v;
#pragma unroll
                for (int j = 0; j < 8; ++j) v[j] = (short)f2bf(buf[(g * 8 + j) * 9 + k]);
                *(s16x8*)&Wt2[((size_t)(k * HID + oc)) * CIN + ic0 + g * 8] = v;
            }
            __syncthreads();
        }
    } else {
        // zero the 68 border cells per image
        const s16x8 z = {0, 0, 0, 0, 0, 0, 0, 0};
        for (int idx = (bid - 768) * 256 + t; idx < 16 * 68 * 256; idx += 64 * 256) {
            int seg = idx & 255;
            int cell = (idx >> 8) % 68;
            int b = idx / (68 * 256);
            int Y, X;
            if (cell < 18)      { Y = 0;         X = cell; }
            else if (cell < 36) { Y = 17;        X = cell - 18; }
            else if (cell < 52) { Y = cell - 35; X = 0; }
            else                { Y = cell - 51; X = 17; }
            *(s16x8*)&Fp[((size_t)(b * 18 + Y) * 18 + X) * CIN + seg * 8] = z;
        }
    }
}

// ============ pass 2: pipelined split-K implicit-GEMM -> Part[4][4096][512] ============
// 512 thr = 8 waves (4M x 2N), wave tile 64x64. 3-buffer LDS (144 KB dynamic).
// Depth-2 prefetch, counted vmcnt(6)+s_barrier at END of step (cross-wave handshake).
// Interior of the step is left to the compiler (auto lgkmcnt interleave).
__global__ __launch_bounds__(512, 2) void k_gemm(const ushort_t* __restrict__ Fp,
                                                 const ushort_t* __restrict__ Wt2,
                                                 float* __restrict__ Part) {
    extern __shared__ ushort_t ldsbuf[];
    ushort_t* As = ldsbuf;                 // [3][A_ELEMS]
    ushort_t* Bs = ldsbuf + 3 * A_ELEMS;   // [3][B_ELEMS]

    int bid = blockIdx.x;          // bid = rb*16 + pair; XCD = bid%8 = pair%8
    int pair = bid & 15, rb = bid >> 4;
    int split = pair >> 2, cb = pair & 3;
    int icBase = split * (CIN / NSPLIT);
    int m0 = rb * BM, oc0 = cb * BN;
    int t = threadIdx.x;
    int wid = t >> 6, lane = t & 63;
    int wr = wid >> 1, wn = wid & 1;
    int hi = lane >> 4, lo = lane & 15;

    f32x4 acc[4][4];
#pragma unroll
    for (int a = 0; a < 4; ++a)
#pragma unroll
        for (int b = 0; b < 4; ++b) acc[a][b] = (f32x4){0.f, 0.f, 0.f, 0.f};

    // staging bases (pre-swizzled global 16B segment; LDS dest linear — rule #21)
    int Abase[4], Bbase[2];
#pragma unroll
    for (int j = 0; j < 4; ++j) {
        int li = j * 512 + t;
        int row = li >> 3;
        int sg = (li & 7) ^ (row & 7);
        int m = m0 + row;
        int b = m >> 8, y = (m >> 4) & 15, x = m & 15;
        Abase[j] = ((b * 18 + y) * 18 + x) * CIN + sg * 8;
    }
#pragma unroll
    for (int j = 0; j < 2; ++j) {
        int li = j * 512 + t;
        int row = li >> 3;
        int sg = (li & 7) ^ (row & 7);
        Bbase[j] = (oc0 + row) * CIN + sg * 8;
    }
    // swizzled ds_read element indices
    int aidx[4][2], bidx[4][2];
#pragma unroll
    for (int fm = 0; fm < 4; ++fm)
#pragma unroll
        for (int ks = 0; ks < 2; ++ks) {
            int r = wr * 64 + fm * 16 + lo;
            aidx[fm][ks] = r * BK + ((ks * 32 + hi * 8) ^ ((r & 7) << 3));
            int rB = wn * 64 + fm * 16 + lo;
            bidx[fm][ks] = rB * BK + ((ks * 32 + hi * 8) ^ ((rB & 7) << 3));
        }

    const int nsteps = (CIN / NSPLIT / BK) * 9;  // 72; kidx inner, ic-chunk outer

#define STAGE_A(BUF, S)                                                              \
    do {                                                                             \
        int kidx_ = (S) % 9, icc_ = (S) / 9;                                         \
        int ak_ = ((kidx_ / 3) * 18 + (kidx_ - 3 * (kidx_ / 3))) * CIN + icBase + icc_ * BK; \
        ushort_t* dA_ = As + (BUF) * A_ELEMS;                                        \
        _Pragma("unroll") for (int j_ = 0; j_ < 4; ++j_)                             \
            gload16(Fp + Abase[j_] + ak_, dA_ + (size_t)(j_ * 512 + t) * 8);         \
    } while (0)
#define STAGE_B(BUF, S)                                                              \
    do {                                                                             \
        int kidx_ = (S) % 9, icc_ = (S) / 9;                                         \
        int bk_ = kidx_ * HID * CIN + icBase + icc_ * BK;                            \
        ushort_t* dB_ = Bs + (BUF) * B_ELEMS;                                        \
        _Pragma("unroll") for (int j_ = 0; j_ < 2; ++j_)                             \
            gload16(Wt2 + Bbase[j_] + bk_, dB_ + (size_t)(j_ * 512 + t) * 8);        \
    } while (0)

    // prologue: tiles 0 and 1 in flight; tile-0 readiness across all waves
    STAGE_A(0, 0); STAGE_B(0, 0);
    STAGE_A(1, 1); STAGE_B(1, 1);
    asm volatile("s_waitcnt vmcnt(6)" ::: "memory");
    __builtin_amdgcn_s_barrier();
    __builtin_amdgcn_sched_barrier(0);

    int bi = 0;
#pragma unroll 1
    for (int step = 0; step < nsteps; ++step) {
        const ushort_t* cA = As + bi * A_ELEMS;
        const ushort_t* cB = Bs + bi * B_ELEMS;
        int b2 = (bi >= 1) ? bi - 1 : 2;  // (bi+2)%3
        // issue next-next tile staging early (DMA, no VGPR use)
        if (step + 2 < nsteps) { STAGE_A(b2, step + 2); STAGE_B(b2, step + 2); }
        // ds_reads + MFMA: compiler-scheduled (auto fine-grained lgkmcnt)
        s16x8 af[4][2], bf[4][2];
#pragma unroll
        for (int ks = 0; ks < 2; ++ks) {
#pragma unroll
            for (int fm = 0; fm < 4; ++fm) af[fm][ks] = *(const s16x8*)&cA[aidx[fm][ks]];
#pragma unroll
            for (int fn = 0; fn < 4; ++fn) bf[fn][ks] = *(const s16x8*)&cB[bidx[fn][ks]];
        }
        __builtin_amdgcn_s_setprio(1);
#pragma unroll
        for (int fm = 0; fm < 4; ++fm)
#pragma unroll
            for (int fn = 0; fn < 4; ++fn)
#pragma unroll
                for (int ks = 0; ks < 2; ++ks)
                    acc[fm][fn] = __builtin_amdgcn_mfma_f32_16x16x32_bf16(
                        af[fm][ks], bf[fn][ks], acc[fm][fn], 0, 0, 0);
        __builtin_amdgcn_s_setprio(0);
        // end-of-step: tile step+1 readiness (counted, cross-wave via barrier)
        if (step + 2 < nsteps) {
            asm volatile("s_waitcnt vmcnt(6)" ::: "memory");
            __builtin_amdgcn_s_barrier();
            __builtin_amdgcn_sched_barrier(0);
        } else if (step + 1 < nsteps) {
            asm volatile("s_waitcnt vmcnt(0)" ::: "memory");
            __builtin_amdgcn_s_barrier();
            __builtin_amdgcn_sched_barrier(0);
        }
        bi = (bi == 2) ? 0 : bi + 1;
    }
#undef STAGE_A
#undef STAGE_B

    // epilogue: store f32 partials
#pragma unroll
    for (int fm = 0; fm < 4; ++fm)
#pragma unroll
        for (int fn = 0; fn < 4; ++fn)
#pragma unroll
            for (int r = 0; r < 4; ++r) {
                int gm = m0 + wr * 64 + fm * 16 + hi * 4 + r;
                int gn = oc0 + wn * 64 + fn * 16 + lo;
                Part[((size_t)split * 4096 + gm) * HID + gn] = acc[fm][fn][r];
            }
}

// ============ pass 3: reduce splits + bias + ReLU + MFMA 1x1 heads ============
// grid 256 blocks x 16 rows; staging by all 256 thr, MFMA+write by wave 0.
__global__ __launch_bounds__(256) void k_heads(const float* __restrict__ Part,
                                               const float* __restrict__ b1,
                                               const float* __restrict__ Wc,
                                               const float* __restrict__ bc,
                                               const float* __restrict__ Wr,
                                               const float* __restrict__ br,
                                               float* __restrict__ conf,
                                               float* __restrict__ reg) {
    extern __shared__ ushort_t hsm[];
    ushort_t* Ah = hsm;              // [16][512] bf16, XOR-swizzled (16 KB)
    ushort_t* Wh = hsm + 16 * HID;   // [48][512] bf16, XOR-swizzled (48 KB)
    int t = threadIdx.x;
    int wid = t >> 6, lane = t & 63;
    int hi = lane >> 4, lo = lane & 15;
    int row0 = blockIdx.x * 16;

    // stage hidden: sum splits + bias + relu -> bf16 swizzled
#pragma unroll
    for (int i = 0; i < 8; ++i) {
        int pos = i * 256 + t;           // [0,2048)
        int r = pos >> 7, c4 = (pos & 127) * 4;
        float4 s = {0.f, 0.f, 0.f, 0.f};
#pragma unroll
        for (int sp = 0; sp < NSPLIT; ++sp) {
            const float4 v = *(const float4*)&Part[((size_t)sp * 4096 + row0 + r) * HID + c4];
            s.x += v.x; s.y += v.y; s.z += v.z; s.w += v.w;
        }
        s.x = fmaxf(s.x + b1[c4 + 0], 0.f);
        s.y = fmaxf(s.y + b1[c4 + 1], 0.f);
        s.z = fmaxf(s.z + b1[c4 + 2], 0.f);
        s.w = fmaxf(s.w + b1[c4 + 3], 0.f);
        s16x4 o = {(short)f2bf(s.x), (short)f2bf(s.y), (short)f2bf(s.z), (short)f2bf(s.w)};
        int phys = r * HID + ((((c4 >> 3) ^ (r & 7)) << 3) | (c4 & 7));
        *(s16x4*)&Ah[phys] = o;
    }
    // stage head weights (rows 0-8: Wc, 9-44: Wr, 45-47: zero)
#pragma unroll
    for (int i = 0; i < 12; ++i) {
        int sid = i * 256 + t;           // [0,3072)
        int o = sid >> 6, sg = sid & 63;
        s16x8 v;
#pragma unroll
        for (int j = 0; j < 8; ++j) {
            float w = 0.f;
            if (o < 9) w = Wc[o * HID + sg * 8 + j];
            else if (o < 45) w = Wr[(size_t)(o - 9) * HID + sg * 8 + j];
            v[j] = (short)f2bf(w);
        }
        *(s16x8*)&Wh[o * HID + ((sg ^ (o & 7)) << 3)] = v;
    }
    __syncthreads();
    if (wid != 0) return;

    f32x4 acc[3];
#pragma unroll
    for (int fn = 0; fn < 3; ++fn) acc[fn] = (f32x4){0.f, 0.f, 0.f, 0.f};
#pragma unroll 1
    for (int kf = 0; kf < 16; ++kf) {
        int rA = lo;
        s16x8 a_ = *(const s16x8*)&Ah[rA * HID + ((kf * 32 + hi * 8) ^ ((rA & 7) << 3))];
#pragma unroll
        for (int fn = 0; fn < 3; ++fn) {
            int rB = fn * 16 + lo;
            s16x8 b_ = *(const s16x8*)&Wh[rB * HID + ((kf * 32 + hi * 8) ^ ((rB & 7) << 3))];
            acc[fn] = __builtin_amdgcn_mfma_f32_16x16x32_bf16(a_, b_, acc[fn], 0, 0, 0);
        }
    }
#pragma unroll
    for (int fn = 0; fn < 3; ++fn)
#pragma unroll
        for (int r = 0; r < 4; ++r) {
            int gm = row0 + hi * 4 + r;
            int o = fn * 16 + lo;
            float v = acc[fn][r];
            if (o < 9) conf[gm * 9 + o] = v + bc[o];
            else if (o < 45) reg[gm * 36 + (o - 9)] = v + br[o - 9];
        }
}

// ============ pass 4: gathers + proposals + losses ============
static __device__ __forceinline__ float softplus(float x) {
    return log1pf(expf(-fabsf(x))) + fmaxf(x, 0.f);
}

__global__ __launch_bounds__(1024) void k_loss(const float* __restrict__ conf,
                                               const float* __restrict__ reg,
                                               const int* __restrict__ pos_ind,
                                               const int* __restrict__ neg_ind,
                                               const float* __restrict__ anc,
                                               const float* __restrict__ gt,
                                               float* __restrict__ out) {
    int t = threadIdx.x;
    float cls = 0.f, rloss = 0.f;
    for (int p = t; p < NPOS; p += 1024) {
        int ind = pos_ind[p];
        {  // conf gather: flat index over [B,9,16,16]
            int b = ind / 2304, r = ind % 2304;
            int c = r >> 8, r2 = r & 255;
            float cv = conf[(b * 256 + r2) * 9 + c];
            cls += softplus(-cv);
        }
        float off[4];
#pragma unroll
        for (int j = 0; j < 4; ++j) {  // reg.reshape(-1,4)[ind]
            int e = 4 * ind + j;
            int b = e / 9216, r = e % 9216;
            int c = r >> 8, r2 = r & 255;
            off[j] = reg[(b * 256 + r2) * 36 + c];
        }
        float ax1 = anc[4 * p], ay1 = anc[4 * p + 1], ax2 = anc[4 * p + 2], ay2 = anc[4 * p + 3];
        float acx = (ax1 + ax2) * 0.5f, acy = (ay1 + ay2) * 0.5f;
        float aw = ax2 - ax1, ah = ay2 - ay1;
        float pcx = acx + off[0] * aw, pcy = acy + off[1] * ah;
        float pw = aw * expf(off[2]), ph = ah * expf(off[3]);
        out[1 + 4 * p + 0] = pcx - pw * 0.5f;
        out[1 + 4 * p + 1] = pcy - ph * 0.5f;
        out[1 + 4 * p + 2] = pcx + pw * 0.5f;
        out[1 + 4 * p + 3] = pcy + ph * 0.5f;
        float gx1 = gt[4 * p], gy1 = gt[4 * p + 1], gx2 = gt[4 * p + 2], gy2 = gt[4 * p + 3];
        float gcx = (gx1 + gx2) * 0.5f, gcy = (gy1 + gy2) * 0.5f;
        float gw = gx2 - gx1, gh = gy2 - gy1;
        float tv[4];
        tv[0] = (gcx - acx) / aw;
        tv[1] = (gcy - acy) / ah;
        tv[2] = logf(gw / aw);
        tv[3] = logf(gh / ah);
#pragma unroll
        for (int j = 0; j < 4; ++j) {
            float d = off[j] - tv[j];
            float ad = fabsf(d);
            rloss += (ad < 1.f) ? 0.5f * d * d : ad - 0.5f;
        }
    }
    for (int q = t; q < NNEG; q += 1024) {
        int ind = neg_ind[q];
        int b = ind / 2304, r = ind % 2304;
        int c = r >> 8, r2 = r & 255;
        float cv = conf[(b * 256 + r2) * 9 + c];
        cls += softplus(cv);
    }
    __shared__ float s1[1024], s2[1024];
    s1[t] = cls;
    s2[t] = rloss;
    __syncthreads();
    for (int s = 512; s > 0; s >>= 1) {
        if (t < s) {
            s1[t] += s1[t + s];
            s2[t] += s2[t + s];
        }
        __syncthreads();
    }
    if (t == 0) out[0] = (s1[0] + 5.f * s2[0]) / 16.f;
}

extern "C" void kernel_launch(void* const* d_in, const int* in_sizes, int n_in,
                              void* d_out, int out_size, void* d_ws, size_t ws_size,
                              hipStream_t stream) {
    const float* F   = (const float*)d_in[0];
    const float* anc = (const float*)d_in[1];
    const float* gt  = (const float*)d_in[2];
    const float* W1  = (const float*)d_in[3];
    const float* b1  = (const float*)d_in[4];
    const float* Wc  = (const float*)d_in[5];
    const float* bc  = (const float*)d_in[6];
    const float* Wr  = (const float*)d_in[7];
    const float* br  = (const float*)d_in[8];
    const int* pos_ind = (const int*)d_in[9];
    const int* neg_ind = (const int*)d_in[10];
    float* out = (float*)d_out;

    char* ws = (char*)d_ws;
    const size_t FP_BYTES   = (size_t)16 * 18 * 18 * CIN * 2;  // 21,233,664
    const size_t WT_BYTES   = (size_t)9 * HID * CIN * 2;       // 18,874,368
    const size_t PART_ONE   = (size_t)4096 * HID * 4;          // 8 MB per split
    const size_t CONF_BYTES = (size_t)4096 * 9 * 4;

    ushort_t* Fp  = (ushort_t*)ws;
    ushort_t* Wt2 = (ushort_t*)(ws + FP_BYTES);
    float* Part   = (float*)(ws + FP_BYTES + WT_BYTES);
    float* conf   = (float*)(ws + FP_BYTES + WT_BYTES + (size_t)NSPLIT * PART_ONE);
    float* reg    = (float*)(ws + FP_BYTES + WT_BYTES + (size_t)NSPLIT * PART_ONE + CONF_BYTES);

    const int GEMM_LDS = 3 * (A_ELEMS + B_ELEMS) * 2;  // 147456
    hipFuncSetAttribute((const void*)k_gemm, hipFuncAttributeMaxDynamicSharedMemorySize, GEMM_LDS);
    const int HEADS_LDS = (16 + 48) * HID * 2;         // 65536
    hipFuncSetAttribute((const void*)k_heads, hipFuncAttributeMaxDynamicSharedMemorySize, HEADS_LDS);

    k_prep<<<832, 256, 0, stream>>>(F, W1, Fp, Wt2);
    k_gemm<<<(4096 / BM) * (HID / BN) * NSPLIT, 512, GEMM_LDS, stream>>>(Fp, Wt2, Part);
    k_heads<<<256, 256, HEADS_LDS, stream>>>(Part, b1, Wc, bc, Wr, br, conf, reg);
    k_loss<<<1, 1024, 0, stream>>>(conf, reg, pos_ind, neg_ind, anc, gt, out);
}